// Round 1
// baseline (694.143 us; speedup 1.0000x reference)
//
#include <hip/hip_runtime.h>

// ---------------- small prep kernels ----------------

__global__ __launch_bounds__(256) void k_deg_init(float* __restrict__ deg, int n) {
    int i = blockIdx.x * 256 + threadIdx.x;
    if (i < n) deg[i] = 1.0f;  // self-loop
}

__global__ __launch_bounds__(256) void k_deg_count(const int* __restrict__ dst,
                                                   float* __restrict__ deg, int e) {
    int i = blockIdx.x * 256 + threadIdx.x;
    if (i < e) atomicAdd(&deg[dst[i]], 1.0f);
}

__global__ __launch_bounds__(256) void k_dinv(const float* __restrict__ deg,
                                              float* __restrict__ dinv, int n) {
    int i = blockIdx.x * 256 + threadIdx.x;
    if (i < n) dinv[i] = rsqrtf(deg[i]);
}

__global__ __launch_bounds__(256) void k_edge_norm(const int* __restrict__ src,
                                                   const int* __restrict__ dst,
                                                   const float* __restrict__ dinv,
                                                   float* __restrict__ norm, int e) {
    int i = blockIdx.x * 256 + threadIdx.x;
    if (i < e) norm[i] = dinv[src[i]] * dinv[dst[i]];
}

// ---------------- scatter-add aggregation ----------------
// One thread per (edge, feature). For LOGF=6 a full wave covers one edge:
// src/dst/norm loads broadcast, gather + atomics are contiguous 256B spans.

template<int LOGF>
__global__ __launch_bounds__(256) void k_scatter(const int* __restrict__ src,
                                                 const int* __restrict__ dst,
                                                 const float* __restrict__ norm,
                                                 const float* __restrict__ h,
                                                 float* __restrict__ agg, int e) {
    int gid = blockIdx.x * 256 + threadIdx.x;
    if (gid < (e << LOGF)) {
        int ed = gid >> LOGF;
        int f  = gid & ((1 << LOGF) - 1);
        int s = src[ed], d = dst[ed];
        float v = h[((size_t)s << LOGF) + f] * norm[ed];
        atomicAdd(&agg[((size_t)d << LOGF) + f], v);
    }
}

// ---------------- GEMM: C[N,OUT] = A[N,K] @ W[K,OUT], fused epilogue ----------------
// Tile: 64 rows per block, 256 threads as 16(tx) x 16(ty); thread computes
// 4 rows x CPT cols. x tile row-major [64][K+4] (pad +4 words keeps float4
// alignment (528B/272B rows) and makes reads 2-way bank aliased = free).
// Epilogue writes both H (raw product, needed by scatter gather) and
// AGG = H*dinv^2 + bias (self-loop + bias fused).
// RELU_IN applies relu while staging A (fuses layer-1 activation).

template<int K, int CPT, bool RELU_IN>
__global__ __launch_bounds__(256) void k_gemm(const float* __restrict__ A,
                                              const float* __restrict__ W,
                                              const float* __restrict__ bias,
                                              const float* __restrict__ dinv,
                                              float* __restrict__ H,
                                              float* __restrict__ AGG, int n) {
    constexpr int OUT  = 16 * CPT;
    constexpr int ROWS = 64;
    constexpr int KS   = K + 4;
    __shared__ __align__(16) float xs[ROWS * KS];
    __shared__ __align__(16) float wsh[K * OUT];

    const int t    = threadIdx.x;
    const int row0 = blockIdx.x * ROWS;

    // stage W (K*OUT floats, linear float4 copy)
    for (int i = t; i < K * OUT / 4; i += 256)
        ((float4*)wsh)[i] = ((const float4*)W)[i];

    // stage A tile (coalesced float4 rows)
    constexpr int RF4 = K / 4;
    for (int i = t; i < ROWS * RF4; i += 256) {
        int r = i / RF4, c4 = i - r * RF4;
        float4 v = make_float4(0.f, 0.f, 0.f, 0.f);
        int gr = row0 + r;
        if (gr < n) {
            v = ((const float4*)(A + (size_t)gr * K))[c4];
            if (RELU_IN) {
                v.x = fmaxf(v.x, 0.f); v.y = fmaxf(v.y, 0.f);
                v.z = fmaxf(v.z, 0.f); v.w = fmaxf(v.w, 0.f);
            }
        }
        *(float4*)(xs + r * KS + c4 * 4) = v;
    }
    __syncthreads();

    const int tx = t & 15, ty = t >> 4;
    float acc[4][CPT];
#pragma unroll
    for (int i = 0; i < 4; ++i)
#pragma unroll
        for (int c = 0; c < CPT; ++c) acc[i][c] = 0.f;

    for (int k = 0; k < K; k += 4) {
        float xr[4][4];
#pragma unroll
        for (int i = 0; i < 4; ++i) {
            float4 xv = *(const float4*)(xs + (ty * 4 + i) * KS + k);
            xr[i][0] = xv.x; xr[i][1] = xv.y; xr[i][2] = xv.z; xr[i][3] = xv.w;
        }
#pragma unroll
        for (int kk = 0; kk < 4; ++kk) {
            float wv[CPT];
            if constexpr (CPT == 4) {
                float4 w4 = *(const float4*)(wsh + (k + kk) * OUT + tx * 4);
                wv[0] = w4.x; wv[1] = w4.y; wv[2] = w4.z; wv[3] = w4.w;
            } else {
                float2 w2 = *(const float2*)(wsh + (k + kk) * OUT + tx * 2);
                wv[0] = w2.x; wv[1] = w2.y;
            }
#pragma unroll
            for (int i = 0; i < 4; ++i)
#pragma unroll
                for (int c = 0; c < CPT; ++c)
                    acc[i][c] = fmaf(xr[i][kk], wv[c], acc[i][c]);
        }
    }

#pragma unroll
    for (int i = 0; i < 4; ++i) {
        int gr = row0 + ty * 4 + i;
        if (gr >= n) continue;
        float di = dinv[gr];
        float d2 = di * di;
        if constexpr (CPT == 4) {
            float4 hv = make_float4(acc[i][0], acc[i][1], acc[i][2], acc[i][3]);
            *(float4*)(H + (size_t)gr * OUT + tx * 4) = hv;
            float4 bv = *(const float4*)(bias + tx * 4);
            *(float4*)(AGG + (size_t)gr * OUT + tx * 4) =
                make_float4(fmaf(hv.x, d2, bv.x), fmaf(hv.y, d2, bv.y),
                            fmaf(hv.z, d2, bv.z), fmaf(hv.w, d2, bv.w));
        } else {
            float2 hv = make_float2(acc[i][0], acc[i][1]);
            *(float2*)(H + (size_t)gr * OUT + tx * 2) = hv;
            float2 bv = *(const float2*)(bias + tx * 2);
            *(float2*)(AGG + (size_t)gr * OUT + tx * 2) =
                make_float2(fmaf(hv.x, d2, bv.x), fmaf(hv.y, d2, bv.y));
        }
    }
}

// ---------------- launch ----------------
// ws layout (floats): deg[N] | dinv[N] | norm[E] | h[64N] | agg1[64N]
// h2 (32N) reuses the h buffer after scatter1. Total 58.4 MB.

extern "C" void kernel_launch(void* const* d_in, const int* in_sizes, int n_in,
                              void* d_out, int out_size, void* d_ws, size_t ws_size,
                              hipStream_t stream) {
    const float* x  = (const float*)d_in[0];
    const float* W1 = (const float*)d_in[1];
    const float* b1 = (const float*)d_in[2];
    const float* W2 = (const float*)d_in[3];
    const float* b2 = (const float*)d_in[4];
    const int*   ei = (const int*)d_in[5];

    const int N = in_sizes[0] / 128;
    const int E = in_sizes[5] / 2;
    const int* src = ei;
    const int* dst = ei + E;

    float* ws   = (float*)d_ws;
    float* deg  = ws;
    float* dinv = deg + N;
    float* norm = dinv + N;
    float* h    = norm + E;           // [N,64]; reused as h2 [N,32]
    float* agg1 = h + (size_t)N * 64; // [N,64]
    float* out  = (float*)d_out;      // [N,32]

    const int nb_n = (N + 255) / 256;
    const int nb_e = (E + 255) / 256;

    k_deg_init <<<nb_n, 256, 0, stream>>>(deg, N);
    k_deg_count<<<nb_e, 256, 0, stream>>>(dst, deg, E);
    k_dinv     <<<nb_n, 256, 0, stream>>>(deg, dinv, N);
    k_edge_norm<<<nb_e, 256, 0, stream>>>(src, dst, dinv, norm, E);

    // layer 1: h = x@W1 ; agg1 = h*dinv^2 + b1 ; scatter edges
    k_gemm<128, 4, false><<<(N + 63) / 64, 256, 0, stream>>>(x, W1, b1, dinv, h, agg1, N);
    {
        long long tot = (long long)E << 6;
        k_scatter<6><<<(int)((tot + 255) / 256), 256, 0, stream>>>(src, dst, norm, h, agg1, E);
    }

    // layer 2: h2 = relu(agg1)@W2 ; out = h2*dinv^2 + b2 ; scatter edges
    k_gemm<64, 2, true><<<(N + 63) / 64, 256, 0, stream>>>(agg1, W2, b2, dinv, h, out, N);
    {
        long long tot = (long long)E << 5;
        k_scatter<5><<<(int)((tot + 255) / 256), 256, 0, stream>>>(src, dst, norm, h, out, E);
    }
}

// Round 2
// 414.319 us; speedup vs baseline: 1.6754x; 1.6754x over previous
//
#include <hip/hip_runtime.h>

// ============ prep: in-degree count, prefix scan -> CSR, dinv ============

__global__ __launch_bounds__(256) void k_zero(int* __restrict__ cnt, int n) {
    int i = blockIdx.x * 256 + threadIdx.x;
    if (i < n) cnt[i] = 0;
}

__global__ __launch_bounds__(256) void k_count(const int* __restrict__ dst,
                                               int* __restrict__ cnt, int e) {
    int i = blockIdx.x * 256 + threadIdx.x;
    if (i < e) atomicAdd(&cnt[dst[i]], 1);
}

// block-level exclusive scan (1024/block) + per-block totals; also emits
// dinv = rsqrt(1 + in_degree) since cnt is already in hand.
__global__ __launch_bounds__(1024) void k_scan1(const int* __restrict__ cnt,
                                                int* __restrict__ rp,
                                                int* __restrict__ bsum,
                                                float* __restrict__ dinv, int n) {
    __shared__ int sm[1024];
    int t = threadIdx.x;
    int i = blockIdx.x * 1024 + t;
    int v = (i < n) ? cnt[i] : 0;
    sm[t] = v;
    __syncthreads();
    for (int off = 1; off < 1024; off <<= 1) {
        int add = (t >= off) ? sm[t - off] : 0;
        __syncthreads();
        sm[t] += add;
        __syncthreads();
    }
    if (i < n) {
        rp[i]   = sm[t] - v;                    // exclusive scan within block
        dinv[i] = rsqrtf(1.0f + (float)v);      // self-loop degree = 1 + in
    }
    if (t == 1023) bsum[blockIdx.x] = sm[1023]; // block total
}

__global__ __launch_bounds__(1024) void k_scan2(int* __restrict__ bsum, int nb) {
    __shared__ int sm[1024];
    int t = threadIdx.x;
    int v = (t < nb) ? bsum[t] : 0;
    sm[t] = v;
    __syncthreads();
    for (int off = 1; off < 1024; off <<= 1) {
        int add = (t >= off) ? sm[t - off] : 0;
        __syncthreads();
        sm[t] += add;
        __syncthreads();
    }
    if (t < nb) bsum[t] = sm[t] - v;            // exclusive block offsets
}

__global__ __launch_bounds__(1024) void k_scan3(int* __restrict__ rp,
                                                const int* __restrict__ bsum, int n) {
    int i = blockIdx.x * 1024 + threadIdx.x;
    if (i < n) rp[i] += bsum[blockIdx.x];
}

// fill CSR: atomic cursor ON rp itself; afterwards rp[d] = end(d) and
// start(d) = (d ? rp[d-1] : 0)  (inclusive-scan convention).
__global__ __launch_bounds__(256) void k_fill(const int* __restrict__ src,
                                              const int* __restrict__ dst,
                                              int* __restrict__ rp,
                                              int* __restrict__ csr, int e) {
    int i = blockIdx.x * 256 + threadIdx.x;
    if (i < e) {
        int pos = atomicAdd(&rp[dst[i]], 1);
        csr[pos] = src[i];
    }
}

// ============ gather-side aggregation (no atomics) ============
// One F-lane group per node (lane = feature). acc starts with the self-loop
// term h'[node]; then accumulate h'[src] over the node's CSR range.
// out[node,f] = acc * dinv[node] + bias[f].

template<int LOGF>
__global__ __launch_bounds__(256) void k_aggregate(const int* __restrict__ rp,
                                                   const int* __restrict__ csr,
                                                   const float* __restrict__ hp,
                                                   const float* __restrict__ dinv,
                                                   const float* __restrict__ bias,
                                                   float* __restrict__ out, int n) {
    constexpr int F = 1 << LOGF;
    int gid  = blockIdx.x * 256 + threadIdx.x;
    int node = gid >> LOGF;
    int f    = gid & (F - 1);
    if (node >= n) return;

    int start = (node == 0) ? 0 : rp[node - 1];
    int end   = rp[node];
    float acc = hp[((size_t)node << LOGF) + f];

    int p = start;
    for (; p + 2 <= end; p += 2) {          // 2-deep: pipeline the gathers
        int s0 = csr[p], s1 = csr[p + 1];
        float v0 = hp[((size_t)s0 << LOGF) + f];
        float v1 = hp[((size_t)s1 << LOGF) + f];
        acc += v0 + v1;
    }
    if (p < end)
        acc += hp[((size_t)csr[p] << LOGF) + f];

    out[((size_t)node << LOGF) + f] = fmaf(acc, dinv[node], bias[f]);
}

// ============ GEMM: H'[N,OUT] = (A[N,K] @ W[K,OUT]) * dinv[row] ============
// 64 rows/block, 256 threads as 16(tx) x 16(ty), 4 rows x CPT cols each.
// RELU_IN applies relu while staging A (fuses previous layer's activation).

template<int K, int CPT, bool RELU_IN>
__global__ __launch_bounds__(256) void k_gemm(const float* __restrict__ A,
                                              const float* __restrict__ W,
                                              const float* __restrict__ dinv,
                                              float* __restrict__ H, int n) {
    constexpr int OUT  = 16 * CPT;
    constexpr int ROWS = 64;
    constexpr int KS   = K + 4;
    __shared__ __align__(16) float xs[ROWS * KS];
    __shared__ __align__(16) float wsh[K * OUT];

    const int t    = threadIdx.x;
    const int row0 = blockIdx.x * ROWS;

    for (int i = t; i < K * OUT / 4; i += 256)
        ((float4*)wsh)[i] = ((const float4*)W)[i];

    constexpr int RF4 = K / 4;
    for (int i = t; i < ROWS * RF4; i += 256) {
        int r = i / RF4, c4 = i - r * RF4;
        float4 v = make_float4(0.f, 0.f, 0.f, 0.f);
        int gr = row0 + r;
        if (gr < n) {
            v = ((const float4*)(A + (size_t)gr * K))[c4];
            if (RELU_IN) {
                v.x = fmaxf(v.x, 0.f); v.y = fmaxf(v.y, 0.f);
                v.z = fmaxf(v.z, 0.f); v.w = fmaxf(v.w, 0.f);
            }
        }
        *(float4*)(xs + r * KS + c4 * 4) = v;
    }
    __syncthreads();

    const int tx = t & 15, ty = t >> 4;
    float acc[4][CPT];
#pragma unroll
    for (int i = 0; i < 4; ++i)
#pragma unroll
        for (int c = 0; c < CPT; ++c) acc[i][c] = 0.f;

    for (int k = 0; k < K; k += 4) {
        float xr[4][4];
#pragma unroll
        for (int i = 0; i < 4; ++i) {
            float4 xv = *(const float4*)(xs + (ty * 4 + i) * KS + k);
            xr[i][0] = xv.x; xr[i][1] = xv.y; xr[i][2] = xv.z; xr[i][3] = xv.w;
        }
#pragma unroll
        for (int kk = 0; kk < 4; ++kk) {
            float wv[CPT];
            if constexpr (CPT == 4) {
                float4 w4 = *(const float4*)(wsh + (k + kk) * OUT + tx * 4);
                wv[0] = w4.x; wv[1] = w4.y; wv[2] = w4.z; wv[3] = w4.w;
            } else {
                float2 w2 = *(const float2*)(wsh + (k + kk) * OUT + tx * 2);
                wv[0] = w2.x; wv[1] = w2.y;
            }
#pragma unroll
            for (int i = 0; i < 4; ++i)
#pragma unroll
                for (int c = 0; c < CPT; ++c)
                    acc[i][c] = fmaf(xr[i][kk], wv[c], acc[i][c]);
        }
    }

#pragma unroll
    for (int i = 0; i < 4; ++i) {
        int gr = row0 + ty * 4 + i;
        if (gr >= n) continue;
        float di = dinv[gr];
        if constexpr (CPT == 4) {
            *(float4*)(H + (size_t)gr * OUT + tx * 4) =
                make_float4(acc[i][0] * di, acc[i][1] * di,
                            acc[i][2] * di, acc[i][3] * di);
        } else {
            *(float2*)(H + (size_t)gr * OUT + tx * 2) =
                make_float2(acc[i][0] * di, acc[i][1] * di);
        }
    }
}

// ============ launch ============
// ws (bytes): cnt[N] | rp[N] | csr[E] | dinv[N] | hp[64N] | agg1[64N] | bsum[1k]
// hp reused as h2' [N,32] for layer 2.  Total ~58.8 MB.

extern "C" void kernel_launch(void* const* d_in, const int* in_sizes, int n_in,
                              void* d_out, int out_size, void* d_ws, size_t ws_size,
                              hipStream_t stream) {
    const float* x  = (const float*)d_in[0];
    const float* W1 = (const float*)d_in[1];
    const float* b1 = (const float*)d_in[2];
    const float* W2 = (const float*)d_in[3];
    const float* b2 = (const float*)d_in[4];
    const int*   ei = (const int*)d_in[5];

    const int N = in_sizes[0] / 128;
    const int E = in_sizes[5] / 2;
    const int* src = ei;
    const int* dst = ei + E;

    char* w = (char*)d_ws;
    int*   cnt  = (int*)w;                     w += (size_t)N * 4;
    int*   rp   = (int*)w;                     w += (size_t)N * 4;
    int*   csr  = (int*)w;                     w += (size_t)E * 4;
    float* dinv = (float*)w;                   w += (size_t)N * 4;
    float* hp   = (float*)w;                   w += (size_t)N * 64 * 4;
    float* agg1 = (float*)w;                   w += (size_t)N * 64 * 4;
    int*   bsum = (int*)w;                     w += 1024 * 4;
    float* out  = (float*)d_out;

    const int nb_n  = (N + 255) / 256;
    const int nb_e  = (E + 255) / 256;
    const int nb_s  = (N + 1023) / 1024;   // scan blocks (<=1024)

    k_zero <<<nb_n, 256, 0, stream>>>(cnt, N);
    k_count<<<nb_e, 256, 0, stream>>>(dst, cnt, E);
    k_scan1<<<nb_s, 1024, 0, stream>>>(cnt, rp, bsum, dinv, N);
    k_scan2<<<1,    1024, 0, stream>>>(bsum, nb_s);
    k_scan3<<<nb_s, 1024, 0, stream>>>(rp, bsum, N);
    k_fill <<<nb_e, 256, 0, stream>>>(src, dst, rp, csr, E);

    // layer 1: hp = (x@W1)*dinv ; agg1 = gather-agg + b1
    k_gemm<128, 4, false><<<(N + 63) / 64, 256, 0, stream>>>(x, W1, dinv, hp, N);
    k_aggregate<6><<<(N * 64 + 255) / 256, 256, 0, stream>>>(rp, csr, hp, dinv, b1, agg1, N);

    // layer 2: hp2 = (relu(agg1)@W2)*dinv ; out = gather-agg + b2
    k_gemm<64, 2, true><<<(N + 63) / 64, 256, 0, stream>>>(agg1, W2, dinv, hp, N);
    k_aggregate<5><<<(N * 32 + 255) / 256, 256, 0, stream>>>(rp, csr, hp, dinv, b2, out, N);
}

// Round 3
// 304.892 us; speedup vs baseline: 2.2767x; 1.3589x over previous
//
#include <hip/hip_runtime.h>

// ============ prep: in-degree count (+rank), prefix scan -> CSR, dinv ============

__global__ __launch_bounds__(256) void k_zero(int* __restrict__ cnt,
                                              int* __restrict__ rpx, int n) {
    int i = blockIdx.x * 256 + threadIdx.x;
    if (i < n) cnt[i] = 0;
    if (i == 0) rpx[0] = 0;
}

// rank[i] = position of edge i within its dst bucket (atomic return value).
// This is the only contended atomic in the whole pipeline.
__global__ __launch_bounds__(256) void k_count(const int* __restrict__ dst,
                                               int* __restrict__ cnt,
                                               int* __restrict__ rank, int e) {
    int i = blockIdx.x * 256 + threadIdx.x;
    if (i < e) rank[i] = atomicAdd(&cnt[dst[i]], 1);
}

// block-level inclusive scan -> rpx[i+1]; per-block totals; dinv = rsqrt(1+deg).
__global__ __launch_bounds__(1024) void k_scan1(const int* __restrict__ cnt,
                                                int* __restrict__ rpx,
                                                int* __restrict__ bsum,
                                                float* __restrict__ dinv, int n) {
    __shared__ int sm[1024];
    int t = threadIdx.x;
    int i = blockIdx.x * 1024 + t;
    int v = (i < n) ? cnt[i] : 0;
    sm[t] = v;
    __syncthreads();
    for (int off = 1; off < 1024; off <<= 1) {
        int add = (t >= off) ? sm[t - off] : 0;
        __syncthreads();
        sm[t] += add;
        __syncthreads();
    }
    if (i < n) {
        rpx[i + 1] = sm[t];                     // inclusive scan (block-local)
        dinv[i]    = rsqrtf(1.0f + (float)v);   // self-loop degree = 1 + in
    }
    if (t == 1023) bsum[blockIdx.x] = sm[1023];
}

__global__ __launch_bounds__(1024) void k_scan2(int* __restrict__ bsum, int nb) {
    __shared__ int sm[1024];
    int t = threadIdx.x;
    int v = (t < nb) ? bsum[t] : 0;
    sm[t] = v;
    __syncthreads();
    for (int off = 1; off < 1024; off <<= 1) {
        int add = (t >= off) ? sm[t - off] : 0;
        __syncthreads();
        sm[t] += add;
        __syncthreads();
    }
    if (t < nb) bsum[t] = sm[t] - v;            // exclusive block offsets
}

__global__ __launch_bounds__(1024) void k_scan3(int* __restrict__ rpx,
                                                const int* __restrict__ bsum, int n) {
    int i = blockIdx.x * 1024 + threadIdx.x;
    if (i < n) rpx[i + 1] += bsum[blockIdx.x];
}

// atomic-free fill: position fully precomputed.
__global__ __launch_bounds__(256) void k_fill(const int* __restrict__ src,
                                              const int* __restrict__ dst,
                                              const int* __restrict__ rank,
                                              const int* __restrict__ rpx,
                                              int* __restrict__ csr, int e) {
    int i = blockIdx.x * 256 + threadIdx.x;
    if (i < e) csr[rpx[dst[i]] + rank[i]] = src[i];
}

// ============ gather-side aggregation (no atomics, float4 lanes) ============
// TPN = F/4 lanes per node, each lane owns one float4 of the row. A 64-lane
// wave services 64/TPN nodes concurrently -> 4x memory-level parallelism vs
// lane-per-feature. 4-deep unroll: 8 independent gathers in flight/thread.
// out[node] = (hp[node] + sum hp[csr-range]) * dinv[node] + bias.

template<int LOGF>
__global__ __launch_bounds__(256) void k_aggregate(const int* __restrict__ rpx,
                                                   const int* __restrict__ csr,
                                                   const float* __restrict__ hp,
                                                   const float* __restrict__ dinv,
                                                   const float* __restrict__ bias,
                                                   float* __restrict__ out, int n) {
    constexpr int TPN = (1 << LOGF) / 4;
    int gid  = blockIdx.x * 256 + threadIdx.x;
    int node = gid / TPN;
    int q    = gid % TPN;
    if (node >= n) return;

    const float4* hp4 = (const float4*)hp;
    int start = rpx[node], end = rpx[node + 1];

    float4 acc0 = hp4[(size_t)node * TPN + q];  // self-loop term
    float4 acc1 = make_float4(0.f, 0.f, 0.f, 0.f);

    int p = start;
    for (; p + 4 <= end; p += 4) {
        int s0 = csr[p], s1 = csr[p + 1], s2 = csr[p + 2], s3 = csr[p + 3];
        float4 v0 = hp4[(size_t)s0 * TPN + q];
        float4 v1 = hp4[(size_t)s1 * TPN + q];
        float4 v2 = hp4[(size_t)s2 * TPN + q];
        float4 v3 = hp4[(size_t)s3 * TPN + q];
        acc0.x += v0.x + v2.x; acc0.y += v0.y + v2.y;
        acc0.z += v0.z + v2.z; acc0.w += v0.w + v2.w;
        acc1.x += v1.x + v3.x; acc1.y += v1.y + v3.y;
        acc1.z += v1.z + v3.z; acc1.w += v1.w + v3.w;
    }
    for (; p < end; ++p) {
        float4 v = hp4[(size_t)csr[p] * TPN + q];
        acc0.x += v.x; acc0.y += v.y; acc0.z += v.z; acc0.w += v.w;
    }

    float di = dinv[node];
    float4 b4 = ((const float4*)bias)[q];
    float4 r;
    r.x = fmaf(acc0.x + acc1.x, di, b4.x);
    r.y = fmaf(acc0.y + acc1.y, di, b4.y);
    r.z = fmaf(acc0.z + acc1.z, di, b4.z);
    r.w = fmaf(acc0.w + acc1.w, di, b4.w);
    ((float4*)out)[(size_t)node * TPN + q] = r;
}

// ============ GEMM: H'[N,OUT] = (A[N,K] @ W[K,OUT]) * dinv[row] ============

template<int K, int CPT, bool RELU_IN>
__global__ __launch_bounds__(256) void k_gemm(const float* __restrict__ A,
                                              const float* __restrict__ W,
                                              const float* __restrict__ dinv,
                                              float* __restrict__ H, int n) {
    constexpr int OUT  = 16 * CPT;
    constexpr int ROWS = 64;
    constexpr int KS   = K + 4;
    __shared__ __align__(16) float xs[ROWS * KS];
    __shared__ __align__(16) float wsh[K * OUT];

    const int t    = threadIdx.x;
    const int row0 = blockIdx.x * ROWS;

    for (int i = t; i < K * OUT / 4; i += 256)
        ((float4*)wsh)[i] = ((const float4*)W)[i];

    constexpr int RF4 = K / 4;
    for (int i = t; i < ROWS * RF4; i += 256) {
        int r = i / RF4, c4 = i - r * RF4;
        float4 v = make_float4(0.f, 0.f, 0.f, 0.f);
        int gr = row0 + r;
        if (gr < n) {
            v = ((const float4*)(A + (size_t)gr * K))[c4];
            if (RELU_IN) {
                v.x = fmaxf(v.x, 0.f); v.y = fmaxf(v.y, 0.f);
                v.z = fmaxf(v.z, 0.f); v.w = fmaxf(v.w, 0.f);
            }
        }
        *(float4*)(xs + r * KS + c4 * 4) = v;
    }
    __syncthreads();

    const int tx = t & 15, ty = t >> 4;
    float acc[4][CPT];
#pragma unroll
    for (int i = 0; i < 4; ++i)
#pragma unroll
        for (int c = 0; c < CPT; ++c) acc[i][c] = 0.f;

    for (int k = 0; k < K; k += 4) {
        float xr[4][4];
#pragma unroll
        for (int i = 0; i < 4; ++i) {
            float4 xv = *(const float4*)(xs + (ty * 4 + i) * KS + k);
            xr[i][0] = xv.x; xr[i][1] = xv.y; xr[i][2] = xv.z; xr[i][3] = xv.w;
        }
#pragma unroll
        for (int kk = 0; kk < 4; ++kk) {
            float wv[CPT];
            if constexpr (CPT == 4) {
                float4 w4 = *(const float4*)(wsh + (k + kk) * OUT + tx * 4);
                wv[0] = w4.x; wv[1] = w4.y; wv[2] = w4.z; wv[3] = w4.w;
            } else {
                float2 w2 = *(const float2*)(wsh + (k + kk) * OUT + tx * 2);
                wv[0] = w2.x; wv[1] = w2.y;
            }
#pragma unroll
            for (int i = 0; i < 4; ++i)
#pragma unroll
                for (int c = 0; c < CPT; ++c)
                    acc[i][c] = fmaf(xr[i][kk], wv[c], acc[i][c]);
        }
    }

#pragma unroll
    for (int i = 0; i < 4; ++i) {
        int gr = row0 + ty * 4 + i;
        if (gr >= n) continue;
        float di = dinv[gr];
        if constexpr (CPT == 4) {
            *(float4*)(H + (size_t)gr * OUT + tx * 4) =
                make_float4(acc[i][0] * di, acc[i][1] * di,
                            acc[i][2] * di, acc[i][3] * di);
        } else {
            *(float2*)(H + (size_t)gr * OUT + tx * 2) =
                make_float2(acc[i][0] * di, acc[i][1] * di);
        }
    }
}

// ============ launch ============
// ws: cnt[N] | rpx[N+1] | csr[E] | dinv[N] | hp[64N] | agg1[64N] | bsum[1k]
// rank[E] overlays agg1 (dead before agg1 is first written). ~58.8 MB.

extern "C" void kernel_launch(void* const* d_in, const int* in_sizes, int n_in,
                              void* d_out, int out_size, void* d_ws, size_t ws_size,
                              hipStream_t stream) {
    const float* x  = (const float*)d_in[0];
    const float* W1 = (const float*)d_in[1];
    const float* b1 = (const float*)d_in[2];
    const float* W2 = (const float*)d_in[3];
    const float* b2 = (const float*)d_in[4];
    const int*   ei = (const int*)d_in[5];

    const int N = in_sizes[0] / 128;
    const int E = in_sizes[5] / 2;
    const int* src = ei;
    const int* dst = ei + E;

    char* w = (char*)d_ws;
    int*   cnt  = (int*)w;                     w += (size_t)N * 4;
    int*   rpx  = (int*)w;                     w += (size_t)(N + 1) * 4;
    int*   csr  = (int*)w;                     w += (size_t)E * 4;
    float* dinv = (float*)w;                   w += (size_t)N * 4;
    float* hp   = (float*)w;                   w += (size_t)N * 64 * 4;
    float* agg1 = (float*)w;                   w += (size_t)N * 64 * 4;
    int*   bsum = (int*)w;                     w += 1024 * 4;
    int*   rank = (int*)agg1;                  // overlay: dead before agg1 write
    float* out  = (float*)d_out;

    const int nb_n = (N + 255) / 256;
    const int nb_e = (E + 255) / 256;
    const int nb_s = (N + 1023) / 1024;

    k_zero <<<nb_n, 256, 0, stream>>>(cnt, rpx, N);
    k_count<<<nb_e, 256, 0, stream>>>(dst, cnt, rank, E);
    k_scan1<<<nb_s, 1024, 0, stream>>>(cnt, rpx, bsum, dinv, N);
    k_scan2<<<1,    1024, 0, stream>>>(bsum, nb_s);
    k_scan3<<<nb_s, 1024, 0, stream>>>(rpx, bsum, N);
    k_fill <<<nb_e, 256, 0, stream>>>(src, dst, rank, rpx, csr, E);

    // layer 1: hp = (x@W1)*dinv ; agg1 = gather-agg + b1
    k_gemm<128, 4, false><<<(N + 63) / 64, 256, 0, stream>>>(x, W1, dinv, hp, N);
    k_aggregate<6><<<(N * 16 + 255) / 256, 256, 0, stream>>>(rpx, csr, hp, dinv, b1, agg1, N);

    // layer 2: hp2 = (relu(agg1)@W2)*dinv ; out = gather-agg + b2
    k_gemm<64, 2, true><<<(N + 63) / 64, 256, 0, stream>>>(agg1, W2, dinv, hp, N);
    k_aggregate<5><<<(N * 8 + 255) / 256, 256, 0, stream>>>(rpx, csr, hp, dinv, b2, out, N);
}

// Round 4
// 253.582 us; speedup vs baseline: 2.7374x; 1.2023x over previous
//
#include <hip/hip_runtime.h>
#include <hip/hip_fp16.h>

// ============ prep: in-degree count (+rank), prefix scan -> CSR, dinv ============

__global__ __launch_bounds__(256) void k_zero(int* __restrict__ cnt,
                                              int* __restrict__ rpx, int n) {
    int i = blockIdx.x * 256 + threadIdx.x;
    if (i < n) cnt[i] = 0;
    if (i == 0) rpx[0] = 0;
}

// rank[i] = position of edge i within its dst bucket (atomic return value).
// This is the only contended atomic in the whole pipeline.
__global__ __launch_bounds__(256) void k_count(const int* __restrict__ dst,
                                               int* __restrict__ cnt,
                                               int* __restrict__ rank, int e) {
    int i = blockIdx.x * 256 + threadIdx.x;
    if (i < e) rank[i] = atomicAdd(&cnt[dst[i]], 1);
}

// block-level inclusive scan -> rpx[i+1]; per-block totals; dinv = rsqrt(1+deg).
__global__ __launch_bounds__(1024) void k_scan1(const int* __restrict__ cnt,
                                                int* __restrict__ rpx,
                                                int* __restrict__ bsum,
                                                float* __restrict__ dinv, int n) {
    __shared__ int sm[1024];
    int t = threadIdx.x;
    int i = blockIdx.x * 1024 + t;
    int v = (i < n) ? cnt[i] : 0;
    sm[t] = v;
    __syncthreads();
    for (int off = 1; off < 1024; off <<= 1) {
        int add = (t >= off) ? sm[t - off] : 0;
        __syncthreads();
        sm[t] += add;
        __syncthreads();
    }
    if (i < n) {
        rpx[i + 1] = sm[t];                     // inclusive scan (block-local)
        dinv[i]    = rsqrtf(1.0f + (float)v);   // self-loop degree = 1 + in
    }
    if (t == 1023) bsum[blockIdx.x] = sm[1023];
}

__global__ __launch_bounds__(1024) void k_scan2(int* __restrict__ bsum, int nb) {
    __shared__ int sm[1024];
    int t = threadIdx.x;
    int v = (t < nb) ? bsum[t] : 0;
    sm[t] = v;
    __syncthreads();
    for (int off = 1; off < 1024; off <<= 1) {
        int add = (t >= off) ? sm[t - off] : 0;
        __syncthreads();
        sm[t] += add;
        __syncthreads();
    }
    if (t < nb) bsum[t] = sm[t] - v;            // exclusive block offsets
}

__global__ __launch_bounds__(1024) void k_scan3(int* __restrict__ rpx,
                                                const int* __restrict__ bsum, int n) {
    int i = blockIdx.x * 1024 + threadIdx.x;
    if (i < n) rpx[i + 1] += bsum[blockIdx.x];
}

// atomic-free fill: position fully precomputed.
__global__ __launch_bounds__(256) void k_fill(const int* __restrict__ src,
                                              const int* __restrict__ dst,
                                              const int* __restrict__ rank,
                                              const int* __restrict__ rpx,
                                              int* __restrict__ csr, int e) {
    int i = blockIdx.x * 256 + threadIdx.x;
    if (i < e) csr[rpx[dst[i]] + rank[i]] = src[i];
}

// ============ gather-side aggregation (fp16 rows, f32 accumulate) ============
// TPN = F/8 lanes per node; each lane owns 8 halves (16 B) of the row.
// 8-deep unroll: 8 independent 16 B gathers in flight per lane (avg degree 16
// -> 2 main iterations). out[node] = (sum) * dinv[node] + bias, in f32.

union Pk8 { float4 f4; __half2 h2[4]; };

__device__ inline void addrow(float acc[8], float4 v) {
    Pk8 u; u.f4 = v;
#pragma unroll
    for (int j = 0; j < 4; ++j) {
        float2 t = __half22float2(u.h2[j]);
        acc[2 * j]     += t.x;
        acc[2 * j + 1] += t.y;
    }
}

template<int LOGF>
__global__ __launch_bounds__(256) void k_aggregate(const int* __restrict__ rpx,
                                                   const int* __restrict__ csr,
                                                   const __half* __restrict__ hp,
                                                   const float* __restrict__ dinv,
                                                   const float* __restrict__ bias,
                                                   float* __restrict__ out, int n) {
    constexpr int F   = 1 << LOGF;
    constexpr int TPN = F / 8;                 // lanes per node
    int gid  = blockIdx.x * 256 + threadIdx.x;
    int node = gid / TPN;
    int q    = gid % TPN;
    if (node >= n) return;

    const float4* hp4 = (const float4*)hp;     // 16 B = 8 halves
    int start = rpx[node], end = rpx[node + 1];

    float acc[8];
#pragma unroll
    for (int j = 0; j < 8; ++j) acc[j] = 0.f;
    addrow(acc, hp4[(size_t)node * TPN + q]);  // self-loop term

    int p = start;
    for (; p + 8 <= end; p += 8) {             // 8 gathers in flight
        int s[8];
#pragma unroll
        for (int j = 0; j < 8; ++j) s[j] = csr[p + j];
        float4 v[8];
#pragma unroll
        for (int j = 0; j < 8; ++j) v[j] = hp4[(size_t)s[j] * TPN + q];
#pragma unroll
        for (int j = 0; j < 8; ++j) addrow(acc, v[j]);
    }
    for (; p + 2 <= end; p += 2) {
        int s0 = csr[p], s1 = csr[p + 1];
        float4 v0 = hp4[(size_t)s0 * TPN + q];
        float4 v1 = hp4[(size_t)s1 * TPN + q];
        addrow(acc, v0);
        addrow(acc, v1);
    }
    if (p < end)
        addrow(acc, hp4[(size_t)csr[p] * TPN + q]);

    float di = dinv[node];
    float4 b0 = ((const float4*)bias)[q * 2];
    float4 b1 = ((const float4*)bias)[q * 2 + 1];
    float4 r0, r1;
    r0.x = fmaf(acc[0], di, b0.x); r0.y = fmaf(acc[1], di, b0.y);
    r0.z = fmaf(acc[2], di, b0.z); r0.w = fmaf(acc[3], di, b0.w);
    r1.x = fmaf(acc[4], di, b1.x); r1.y = fmaf(acc[5], di, b1.y);
    r1.z = fmaf(acc[6], di, b1.z); r1.w = fmaf(acc[7], di, b1.w);
    float4* o4 = (float4*)out;
    o4[(size_t)node * (F / 4) + q * 2]     = r0;
    o4[(size_t)node * (F / 4) + q * 2 + 1] = r1;
}

// ============ GEMM: H'[N,OUT] = fp16( (A[N,K] @ W[K,OUT]) * dinv[row] ) ============
// f32 compute, fp16 store (feeds the gather kernel). RELU_IN fuses the previous
// layer's activation while staging A.

template<int K, int CPT, bool RELU_IN>
__global__ __launch_bounds__(256) void k_gemm(const float* __restrict__ A,
                                              const float* __restrict__ W,
                                              const float* __restrict__ dinv,
                                              __half* __restrict__ H, int n) {
    constexpr int OUT  = 16 * CPT;
    constexpr int ROWS = 64;
    constexpr int KS   = K + 4;
    __shared__ __align__(16) float xs[ROWS * KS];
    __shared__ __align__(16) float wsh[K * OUT];

    const int t    = threadIdx.x;
    const int row0 = blockIdx.x * ROWS;

    for (int i = t; i < K * OUT / 4; i += 256)
        ((float4*)wsh)[i] = ((const float4*)W)[i];

    constexpr int RF4 = K / 4;
    for (int i = t; i < ROWS * RF4; i += 256) {
        int r = i / RF4, c4 = i - r * RF4;
        float4 v = make_float4(0.f, 0.f, 0.f, 0.f);
        int gr = row0 + r;
        if (gr < n) {
            v = ((const float4*)(A + (size_t)gr * K))[c4];
            if (RELU_IN) {
                v.x = fmaxf(v.x, 0.f); v.y = fmaxf(v.y, 0.f);
                v.z = fmaxf(v.z, 0.f); v.w = fmaxf(v.w, 0.f);
            }
        }
        *(float4*)(xs + r * KS + c4 * 4) = v;
    }
    __syncthreads();

    const int tx = t & 15, ty = t >> 4;
    float acc[4][CPT];
#pragma unroll
    for (int i = 0; i < 4; ++i)
#pragma unroll
        for (int c = 0; c < CPT; ++c) acc[i][c] = 0.f;

    for (int k = 0; k < K; k += 4) {
        float xr[4][4];
#pragma unroll
        for (int i = 0; i < 4; ++i) {
            float4 xv = *(const float4*)(xs + (ty * 4 + i) * KS + k);
            xr[i][0] = xv.x; xr[i][1] = xv.y; xr[i][2] = xv.z; xr[i][3] = xv.w;
        }
#pragma unroll
        for (int kk = 0; kk < 4; ++kk) {
            float wv[CPT];
            if constexpr (CPT == 4) {
                float4 w4 = *(const float4*)(wsh + (k + kk) * OUT + tx * 4);
                wv[0] = w4.x; wv[1] = w4.y; wv[2] = w4.z; wv[3] = w4.w;
            } else {
                float2 w2 = *(const float2*)(wsh + (k + kk) * OUT + tx * 2);
                wv[0] = w2.x; wv[1] = w2.y;
            }
#pragma unroll
            for (int i = 0; i < 4; ++i)
#pragma unroll
                for (int c = 0; c < CPT; ++c)
                    acc[i][c] = fmaf(xr[i][kk], wv[c], acc[i][c]);
        }
    }

#pragma unroll
    for (int i = 0; i < 4; ++i) {
        int gr = row0 + ty * 4 + i;
        if (gr >= n) continue;
        float di = dinv[gr];
        if constexpr (CPT == 4) {
            union { __half2 h2[2]; uint2 u2; } pk;
            pk.h2[0] = __floats2half2_rn(acc[i][0] * di, acc[i][1] * di);
            pk.h2[1] = __floats2half2_rn(acc[i][2] * di, acc[i][3] * di);
            *(uint2*)(H + (size_t)gr * OUT + tx * 4) = pk.u2;
        } else {
            *(__half2*)(H + (size_t)gr * OUT + tx * 2) =
                __floats2half2_rn(acc[i][0] * di, acc[i][1] * di);
        }
    }
}

// ============ launch ============
// ws: cnt[N] | rpx[N+1] | csr[E] | dinv[N] | hp[64N halves] | agg1[64N f32] | bsum
// rank[E] overlays agg1 (dead before agg1 is first written). hp reused as
// layer-2 fp16 rows [N,32].

extern "C" void kernel_launch(void* const* d_in, const int* in_sizes, int n_in,
                              void* d_out, int out_size, void* d_ws, size_t ws_size,
                              hipStream_t stream) {
    const float* x  = (const float*)d_in[0];
    const float* W1 = (const float*)d_in[1];
    const float* b1 = (const float*)d_in[2];
    const float* W2 = (const float*)d_in[3];
    const float* b2 = (const float*)d_in[4];
    const int*   ei = (const int*)d_in[5];

    const int N = in_sizes[0] / 128;
    const int E = in_sizes[5] / 2;
    const int* src = ei;
    const int* dst = ei + E;

    char* w = (char*)d_ws;
    int*    cnt  = (int*)w;                    w += (size_t)N * 4;
    int*    rpx  = (int*)w;                    w += (size_t)(N + 1) * 4 + 4; // keep 16B align
    int*    csr  = (int*)w;                    w += (size_t)E * 4;
    float*  dinv = (float*)w;                  w += (size_t)N * 4;
    __half* hp   = (__half*)w;                 w += (size_t)N * 64 * 2;
    float*  agg1 = (float*)w;                  w += (size_t)N * 64 * 4;
    int*    bsum = (int*)w;                    w += 1024 * 4;
    int*    rank = (int*)agg1;                 // overlay: dead before agg1 write
    float*  out  = (float*)d_out;

    const int nb_n = (N + 255) / 256;
    const int nb_e = (E + 255) / 256;
    const int nb_s = (N + 1023) / 1024;

    k_zero <<<nb_n, 256, 0, stream>>>(cnt, rpx, N);
    k_count<<<nb_e, 256, 0, stream>>>(dst, cnt, rank, E);
    k_scan1<<<nb_s, 1024, 0, stream>>>(cnt, rpx, bsum, dinv, N);
    k_scan2<<<1,    1024, 0, stream>>>(bsum, nb_s);
    k_scan3<<<nb_s, 1024, 0, stream>>>(rpx, bsum, N);
    k_fill <<<nb_e, 256, 0, stream>>>(src, dst, rank, rpx, csr, E);

    // layer 1: hp = fp16((x@W1)*dinv) ; agg1 = gather-agg + b1 (f32)
    k_gemm<128, 4, false><<<(N + 63) / 64, 256, 0, stream>>>(x, W1, dinv, hp, N);
    k_aggregate<6><<<(N * 8 + 255) / 256, 256, 0, stream>>>(rpx, csr, hp, dinv, b1, agg1, N);

    // layer 2: hp2 = fp16((relu(agg1)@W2)*dinv) ; out = gather-agg + b2 (f32)
    k_gemm<64, 2, true><<<(N + 63) / 64, 256, 0, stream>>>(agg1, W2, dinv, hp, N);
    k_aggregate<5><<<(N * 4 + 255) / 256, 256, 0, stream>>>(rpx, csr, hp, dinv, b2, out, N);
}